// Round 1
// baseline (242.701 us; speedup 1.0000x reference)
//
#include <hip/hip_runtime.h>
#include <hip/hip_bf16.h>

#define EDIM 128
#define KNEG 5

// Half-wave (32 lanes) per batch element. Each lane reads a float4 of the
// 128-float row -> 512 B coalesced per row gather. 6 dot products reduced
// via 5 shfl_xor steps (stay within the 32-lane half). log_sigmoid spread
// across lanes 0..5 of each half.
__global__ __launch_bounds__(256) void sgns_loss_kernel(
    const float* __restrict__ second_emb,
    const float* __restrict__ context_emb,
    const int* __restrict__ v_i,
    const int* __restrict__ v_j,
    const int* __restrict__ negs,
    float* __restrict__ out,
    int B)
{
    const int tid   = blockIdx.x * blockDim.x + threadIdx.x;
    const int lane  = threadIdx.x & 63;
    const int half  = lane >> 5;   // 0 or 1: which element this half-wave owns
    const int sub   = lane & 31;   // lane within the half-wave
    const int gwave = tid >> 6;
    const int nwaves = (gridDim.x * blockDim.x) >> 6;

    float acc = 0.0f;

    for (int base = gwave * 2; base < B; base += nwaves * 2) {
        const int b = base + half;          // B is even; both halves in-range
        // 7 indices for this element (uniform within the half-wave)
        const int ii = v_i[b];
        const int jj = v_j[b];
        const int n0 = negs[0 * B + b];
        const int n1 = negs[1 * B + b];
        const int n2 = negs[2 * B + b];
        const int n3 = negs[3 * B + b];
        const int n4 = negs[4 * B + b];

        const float4* ri = (const float4*)(second_emb  + (size_t)ii * EDIM);
        const float4* r0 = (const float4*)(context_emb + (size_t)jj * EDIM);
        const float4* r1 = (const float4*)(context_emb + (size_t)n0 * EDIM);
        const float4* r2 = (const float4*)(context_emb + (size_t)n1 * EDIM);
        const float4* r3 = (const float4*)(context_emb + (size_t)n2 * EDIM);
        const float4* r4 = (const float4*)(context_emb + (size_t)n3 * EDIM);
        const float4* r5 = (const float4*)(context_emb + (size_t)n4 * EDIM);

        // Issue all loads up front for ILP
        const float4 a  = ri[sub];
        const float4 o0 = r0[sub];
        const float4 o1 = r1[sub];
        const float4 o2 = r2[sub];
        const float4 o3 = r3[sub];
        const float4 o4 = r4[sub];
        const float4 o5 = r5[sub];

        float d[6];
        d[0] = a.x * o0.x + a.y * o0.y + a.z * o0.z + a.w * o0.w;
        d[1] = a.x * o1.x + a.y * o1.y + a.z * o1.z + a.w * o1.w;
        d[2] = a.x * o2.x + a.y * o2.y + a.z * o2.z + a.w * o2.w;
        d[3] = a.x * o3.x + a.y * o3.y + a.z * o3.z + a.w * o3.w;
        d[4] = a.x * o4.x + a.y * o4.y + a.z * o4.z + a.w * o4.w;
        d[5] = a.x * o5.x + a.y * o5.y + a.z * o5.z + a.w * o5.w;

        // Butterfly reduce within each 32-lane half (offsets 1..16 never
        // cross the bit-5 boundary). After this every lane of the half has
        // all 6 full dot products.
        #pragma unroll
        for (int off = 1; off <= 16; off <<= 1) {
            #pragma unroll
            for (int m = 0; m < 6; ++m)
                d[m] += __shfl_xor(d[m], off);
        }

        // lanes sub==0..5: lane s evaluates log_sigmoid of dot s
        // (s==0 is the positive term: logsig(+d0); s>=1: logsig(-ds))
        float x = d[0];
        x = (sub == 1) ? -d[1] : x;
        x = (sub == 2) ? -d[2] : x;
        x = (sub == 3) ? -d[3] : x;
        x = (sub == 4) ? -d[4] : x;
        x = (sub == 5) ? -d[5] : x;
        if (sub < 6) {
            // stable log_sigmoid
            acc += fminf(x, 0.0f) - log1pf(expf(-fabsf(x)));
        }
    }

    // Reduce acc over the full wave (64 lanes)
    #pragma unroll
    for (int off = 32; off >= 1; off >>= 1)
        acc += __shfl_xor(acc, off);

    __shared__ float wsum[4];
    const int wid = threadIdx.x >> 6;
    if ((threadIdx.x & 63) == 0) wsum[wid] = acc;
    __syncthreads();

    if (threadIdx.x == 0) {
        float s = wsum[0] + wsum[1] + wsum[2] + wsum[3];
        atomicAdd(out, s * (-1.0f / (float)B));
    }
}

extern "C" void kernel_launch(void* const* d_in, const int* in_sizes, int n_in,
                              void* d_out, int out_size, void* d_ws, size_t ws_size,
                              hipStream_t stream) {
    const float* second_emb  = (const float*)d_in[0];
    const float* context_emb = (const float*)d_in[1];
    const int*   v_i  = (const int*)d_in[2];
    const int*   v_j  = (const int*)d_in[3];
    const int*   negs = (const int*)d_in[4];
    float* out = (float*)d_out;
    const int B = in_sizes[2];

    // d_out is re-poisoned to 0xAA before every timed launch; zero it first.
    hipMemsetAsync(d_out, 0, sizeof(float), stream);

    dim3 block(256);
    dim3 grid(1024);
    sgns_loss_kernel<<<grid, block, 0, stream>>>(
        second_emb, context_emb, v_i, v_j, negs, out, B);
}

// Round 2
// 239.882 us; speedup vs baseline: 1.0118x; 1.0118x over previous
//
#include <hip/hip_runtime.h>
#include <hip/hip_bf16.h>

#define EDIM 128
#define KNEG 5

// Half-wave (32 lanes) per batch element, 2 elements per half-wave per
// iteration (14 row-loads in flight). Each lane reads a float4 of the
// 128-float row -> 512 B coalesced per row gather. Dots reduced via 5
// shfl_xor steps (offsets 1..16 stay within the 32-lane half).
__global__ __launch_bounds__(256) void sgns_loss_kernel(
    const float* __restrict__ second_emb,
    const float* __restrict__ context_emb,
    const int* __restrict__ v_i,
    const int* __restrict__ v_j,
    const int* __restrict__ negs,
    float* __restrict__ out,
    int B)
{
    const int tid   = blockIdx.x * blockDim.x + threadIdx.x;
    const int lane  = threadIdx.x & 63;
    const int half  = lane >> 5;   // 0 or 1: which pair this half-wave owns
    const int sub   = lane & 31;   // lane within the half-wave
    const int gwave = tid >> 6;
    const int nwaves = (gridDim.x * blockDim.x) >> 6;

    float acc = 0.0f;

    // Each wave handles 4 consecutive elements per iteration:
    // half 0 -> base+0, base+1 ; half 1 -> base+2, base+3.
    for (int base = gwave * 4; base < B; base += nwaves * 4) {
        const int b0 = base + half * 2;     // B % 4 == 0; always in-range
        const int b1 = b0 + 1;

        const int i0  = v_i[b0];
        const int i1  = v_i[b1];
        const int j0  = v_j[b0];
        const int j1  = v_j[b1];
        const int n00 = negs[0 * B + b0];
        const int n01 = negs[1 * B + b0];
        const int n02 = negs[2 * B + b0];
        const int n03 = negs[3 * B + b0];
        const int n04 = negs[4 * B + b0];
        const int n10 = negs[0 * B + b1];
        const int n11 = negs[1 * B + b1];
        const int n12 = negs[2 * B + b1];
        const int n13 = negs[3 * B + b1];
        const int n14 = negs[4 * B + b1];

        // Issue all 14 row loads up front for max memory-level parallelism
        const float4 a0  = ((const float4*)(second_emb  + (size_t)i0  * EDIM))[sub];
        const float4 a1  = ((const float4*)(second_emb  + (size_t)i1  * EDIM))[sub];
        const float4 p0  = ((const float4*)(context_emb + (size_t)j0  * EDIM))[sub];
        const float4 p1  = ((const float4*)(context_emb + (size_t)j1  * EDIM))[sub];
        const float4 q00 = ((const float4*)(context_emb + (size_t)n00 * EDIM))[sub];
        const float4 q01 = ((const float4*)(context_emb + (size_t)n01 * EDIM))[sub];
        const float4 q02 = ((const float4*)(context_emb + (size_t)n02 * EDIM))[sub];
        const float4 q03 = ((const float4*)(context_emb + (size_t)n03 * EDIM))[sub];
        const float4 q04 = ((const float4*)(context_emb + (size_t)n04 * EDIM))[sub];
        const float4 q10 = ((const float4*)(context_emb + (size_t)n10 * EDIM))[sub];
        const float4 q11 = ((const float4*)(context_emb + (size_t)n11 * EDIM))[sub];
        const float4 q12 = ((const float4*)(context_emb + (size_t)n12 * EDIM))[sub];
        const float4 q13 = ((const float4*)(context_emb + (size_t)n13 * EDIM))[sub];
        const float4 q14 = ((const float4*)(context_emb + (size_t)n14 * EDIM))[sub];

        float d[12];
        d[0]  = a0.x * p0.x  + a0.y * p0.y  + a0.z * p0.z  + a0.w * p0.w;
        d[1]  = a0.x * q00.x + a0.y * q00.y + a0.z * q00.z + a0.w * q00.w;
        d[2]  = a0.x * q01.x + a0.y * q01.y + a0.z * q01.z + a0.w * q01.w;
        d[3]  = a0.x * q02.x + a0.y * q02.y + a0.z * q02.z + a0.w * q02.w;
        d[4]  = a0.x * q03.x + a0.y * q03.y + a0.z * q03.z + a0.w * q03.w;
        d[5]  = a0.x * q04.x + a0.y * q04.y + a0.z * q04.z + a0.w * q04.w;
        d[6]  = a1.x * p1.x  + a1.y * p1.y  + a1.z * p1.z  + a1.w * p1.w;
        d[7]  = a1.x * q10.x + a1.y * q10.y + a1.z * q10.z + a1.w * q10.w;
        d[8]  = a1.x * q11.x + a1.y * q11.y + a1.z * q11.z + a1.w * q11.w;
        d[9]  = a1.x * q12.x + a1.y * q12.y + a1.z * q12.z + a1.w * q12.w;
        d[10] = a1.x * q13.x + a1.y * q13.y + a1.z * q13.z + a1.w * q13.w;
        d[11] = a1.x * q14.x + a1.y * q14.y + a1.z * q14.z + a1.w * q14.w;

        // Butterfly reduce within each 32-lane half; afterwards every lane
        // of the half holds all 12 full dot products.
        #pragma unroll
        for (int off = 1; off <= 16; off <<= 1) {
            #pragma unroll
            for (int m = 0; m < 12; ++m)
                d[m] += __shfl_xor(d[m], off);
        }

        // Distribute the 12 log_sigmoid evals: lanes 0..5 take element b0
        // (dot s), lanes 8..13 take element b1 (dot s-8+6).
        float x = 0.0f;
        bool active = false;
        if (sub < 6) {
            x = (sub == 0) ? d[0] : -d[sub];
            active = true;
        } else if (sub >= 8 && sub < 14) {
            const int s = sub - 8;
            x = (s == 0) ? d[6] : -d[6 + s];
            active = true;
        }
        if (active) {
            acc += fminf(x, 0.0f) - log1pf(expf(-fabsf(x)));
        }
    }

    // Reduce acc over the full wave (64 lanes)
    #pragma unroll
    for (int off = 32; off >= 1; off >>= 1)
        acc += __shfl_xor(acc, off);

    __shared__ float wsum[4];
    const int wid = threadIdx.x >> 6;
    if ((threadIdx.x & 63) == 0) wsum[wid] = acc;
    __syncthreads();

    if (threadIdx.x == 0) {
        float s = wsum[0] + wsum[1] + wsum[2] + wsum[3];
        atomicAdd(out, s * (-1.0f / (float)B));
    }
}

extern "C" void kernel_launch(void* const* d_in, const int* in_sizes, int n_in,
                              void* d_out, int out_size, void* d_ws, size_t ws_size,
                              hipStream_t stream) {
    const float* second_emb  = (const float*)d_in[0];
    const float* context_emb = (const float*)d_in[1];
    const int*   v_i  = (const int*)d_in[2];
    const int*   v_j  = (const int*)d_in[3];
    const int*   negs = (const int*)d_in[4];
    float* out = (float*)d_out;
    const int B = in_sizes[2];

    // d_out is re-poisoned to 0xAA before every timed launch; zero it first.
    hipMemsetAsync(d_out, 0, sizeof(float), stream);

    // 2048 blocks x 4 waves = 8192 waves = 32 waves/CU (full wave-slot
    // occupancy at VGPR=32). Each wave covers 4 elements/iteration.
    dim3 block(256);
    dim3 grid(2048);
    sgns_loss_kernel<<<grid, block, 0, stream>>>(
        second_emb, context_emb, v_i, v_j, negs, out, B);
}